// Round 16
// baseline (350.217 us; speedup 1.0000x reference)
//
#include <hip/hip_runtime.h>
#include <math.h>

#define HW 65536

typedef __attribute__((ext_vector_type(8))) short short8;
typedef __attribute__((ext_vector_type(4))) float f32x4;

__device__ __forceinline__ unsigned bf16rne(float f) {
  union { float f; unsigned u; } a; a.f = f;
  return (a.u + 0x7fffu + ((a.u >> 16) & 1u)) >> 16;
}
__device__ __forceinline__ float bf16tof(unsigned h) {
  union { unsigned u; float f; } a; a.u = h << 16;
  return a.f;
}
// fast gelu: Abramowitz-Stegun 7.1.26 erf, |abs err| <= 1.5e-7, branch-free
__device__ __forceinline__ float gelu(float v) {
  float ax = fabsf(v) * 0.70710678118654752f;
  float t = 1.0f / fmaf(0.3275911f, ax, 1.0f);
  float p = t * (0.254829592f +
           t * (-0.284496736f +
           t * (1.421413741f +
           t * (-1.453152027f +
           t * 1.061405429f))));
  float e = __expf(-ax * ax);
  float er = copysignf(fmaf(-p, e, 1.0f), v);
  return 0.5f * v * (1.0f + er);
}

// ---------- tables + weight pre-split (merged) ----------
__global__ __launch_bounds__(256) void k_tables(float* __restrict__ cosT, float* __restrict__ sinT,
                                                ushort* __restrict__ eah, ushort* __restrict__ eal,
                                                ushort* __restrict__ e2h, ushort* __restrict__ e2l,
                                                const float* __restrict__ ww, const float* __restrict__ w1,
                                                ushort* __restrict__ wh, ushort* __restrict__ wl,
                                                ushort* __restrict__ w1h, ushort* __restrict__ w1l) {
  int idx = blockIdx.x * 256 + threadIdx.x;   // 144*256 = 36864
  const float w = 0.0245436926061702596f;     // 2*pi/256
  if (idx < 4096) {
    int k = idx >> 8, xx = idx & 255;
    int t = (k * xx) & 255;
    float ang = (float)t * w;
    cosT[idx] = cosf(ang);
    sinT[idx] = sinf(ang);
  } else if (idx < 12288) {
    int e = idx - 4096;
    int j = e >> 8, xx = e & 255;
    int k = j >> 1;
    int t = (k * xx) & 255;
    float ang = (float)t * w;
    float val = (j & 1) ? -sinf(ang) : cosf(ang);
    unsigned hi = bf16rne(val);
    unsigned lo = bf16rne(val - bf16tof(hi));
    eah[j * 256 + xx] = (ushort)hi;
    eal[j * 256 + xx] = (ushort)lo;
    e2h[xx * 32 + j] = (ushort)hi;
    e2l[xx * 32 + j] = (ushort)lo;
  } else if (idx < 28672) {
    int j = idx - 12288;
    float v = ww[j];
    unsigned hi = bf16rne(v);
    wh[j] = (ushort)hi;
    wl[j] = (ushort)bf16rne(v - bf16tof(hi));
  } else {
    int j = idx - 28672;                      // 8192
    float v = w1[j];
    unsigned hi = bf16rne(v);
    w1h[j] = (ushort)hi;
    w1l[j] = (ushort)bf16rne(v - bf16tof(hi));
  }
}

// ---------- fc0: h plane (bf16) + fused full-row x-DFT -> A2 part 0 ----------
// A2: A2[((b*64+c)*256+y)*64 + part*32 + j], j=2k:Re, 2k+1:Im.
__global__ __launch_bounds__(256) void k_fc0(const float* __restrict__ x, const float* __restrict__ w,
                                             const float* __restrict__ b,
                                             const ushort* __restrict__ eah, const ushort* __restrict__ eal,
                                             ushort* __restrict__ hh, float* __restrict__ A2) {
  int bid = blockIdx.x;                 // 1024 = B*H
  int bb = bid >> 8, y = bid & 255;
  int tid = threadIdx.x;
  __shared__ float ws[192];
  __shared__ float bs[64];
  __shared__ __align__(16) ushort XsH[256 * 66];
  if (tid < 192) ws[tid] = w[tid];
  if (tid < 64) bs[tid] = b[tid];
  __syncthreads();
  const float* xrow = x + ((size_t)(bb * 3) * 256 + y) * 256;
#pragma unroll
  for (int rep = 0; rep < 8; ++rep) {
    int flat = rep * 256 + tid;       // (pixel p, 8-c group q)
    int p = flat >> 3, q = flat & 7;
    float v0 = xrow[p], v1 = xrow[p + HW], v2 = xrow[p + 2 * HW];
    short8 H;
#pragma unroll
    for (int i = 0; i < 8; ++i) {
      int o = q * 8 + i;
      float v = bs[o] + ws[o * 3] * v0 + ws[o * 3 + 1] * v1 + ws[o * 3 + 2] * v2;
      H[i] = (short)bf16rne(v);
    }
    size_t nb = ((size_t)bid * 256 + p) * 64 + q * 8;
    *(short8*)&hh[nb] = H;
    *(short8*)&XsH[p * 66 + q * 8] = H;
  }
  __syncthreads();
  // fused F1: wave = c 16-slice, contract over full 256 x; write part 0
  int lane = tid & 63, wv = tid >> 6;
  int lm = lane & 15, lg = lane >> 4;
  f32x4 d0 = (f32x4){0.f, 0.f, 0.f, 0.f};
  f32x4 d1 = (f32x4){0.f, 0.f, 0.f, 0.f};
  int c = wv * 16 + lm;
#pragma unroll
  for (int kc = 0; kc < 8; ++kc) {
    int x0 = kc * 32 + lg * 8;
    short8 bh;
#pragma unroll
    for (int i = 0; i < 8; ++i) bh[i] = (short)XsH[(x0 + i) * 66 + c];
    short8 a0h = *(const short8*)&eah[lm * 256 + x0];
    short8 a0l = *(const short8*)&eal[lm * 256 + x0];
    short8 a1h = *(const short8*)&eah[(16 + lm) * 256 + x0];
    short8 a1l = *(const short8*)&eal[(16 + lm) * 256 + x0];
    d0 = __builtin_amdgcn_mfma_f32_16x16x32_bf16(a0h, bh, d0, 0, 0, 0);
    d0 = __builtin_amdgcn_mfma_f32_16x16x32_bf16(a0l, bh, d0, 0, 0, 0);
    d1 = __builtin_amdgcn_mfma_f32_16x16x32_bf16(a1h, bh, d1, 0, 0, 0);
    d1 = __builtin_amdgcn_mfma_f32_16x16x32_bf16(a1l, bh, d1, 0, 0, 0);
  }
  size_t row = ((size_t)(bb * 64 + c) * 256 + y) * 64;
  *(float4*)&A2[row + lg * 4] = make_float4(d0[0], d0[1], d0[2], d0[3]);
  *(float4*)&A2[row + 16 + lg * 4] = make_float4(d1[0], d1[1], d1[2], d1[3]);
}

// ---------- F2: col DFT over y (y-split halves); sums nparts partials; writes X partials ----------
__global__ __launch_bounds__(256) void k_f2(const float* __restrict__ A2, const float* __restrict__ cosT,
                                            const float* __restrict__ sinT, float2* __restrict__ Xp,
                                            int nparts) {
  int bid = blockIdx.x;                 // 512 = plane*2 + yh
  int plane = bid >> 1, yh = bid & 1;
  int tid = threadIdx.x;
  __shared__ float2 As[128 * 16];
  __shared__ float ct[16 * 129];
  __shared__ float stt[16 * 129];
  const float2* Ap = (const float2*)A2 + (size_t)plane * 8192;   // 32 float2 per y
#pragma unroll
  for (int rep = 0; rep < 8; ++rep) {
    int flat = rep * 256 + tid;       // 2048: y' (128) x j (16)
    int yp = flat >> 4, j = flat & 15;
    int y = yh * 128 + yp;
    float2 v = Ap[y * 32 + j];
    if (nparts == 2) {
      float2 v1 = Ap[y * 32 + 16 + j];
      v.x += v1.x; v.y += v1.y;
    }
    As[yp * 16 + j] = v;
  }
#pragma unroll
  for (int rep = 0; rep < 8; ++rep) {
    int flat = rep * 256 + tid;       // 2048: ky (16) x y' (128)
    int ky = flat >> 7, yp = flat & 127;
    ct[ky * 129 + yp] = cosT[ky * 256 + yh * 128 + yp];
    stt[ky * 129 + yp] = sinT[ky * 256 + yh * 128 + yp];
  }
  __syncthreads();
  int ky = tid >> 4, kx = tid & 15;
  float xr = 0.f, xi = 0.f;
#pragma unroll 4
  for (int yp = 0; yp < 128; ++yp) {
    float2 a = As[yp * 16 + kx];
    float c = ct[ky * 129 + yp], s = stt[ky * 129 + yp];
    xr += c * a.x + s * a.y;
    xi += c * a.y - s * a.x;
  }
  Xp[(size_t)plane * 512 + yh * 256 + tid] = make_float2(xr, xi);
}

// ---------- MIXINV: fused mix + inv1. Block = (o, b). ----------
__global__ __launch_bounds__(256) void k_mixinv(const float2* __restrict__ Xp,
                                                const float* __restrict__ wr, const float* __restrict__ wi,
                                                const float* __restrict__ cosT, const float* __restrict__ sinT,
                                                ushort* __restrict__ gh, ushort* __restrict__ gl) {
  int bid = blockIdx.x;                 // 256 = o*4 + b
  int o = bid >> 2, b = bid & 3;
  int tid = threadIdx.x;
  int cg = tid >> 6, m2 = tid & 63;
  __shared__ float2 red[1024];
  __shared__ float2 Ys[256];

  float yr[4] = {0.f, 0.f, 0.f, 0.f}, yi[4] = {0.f, 0.f, 0.f, 0.f};
#pragma unroll 4
  for (int cc = 0; cc < 16; ++cc) {
    int c = cg * 16 + cc;
    size_t wbx = (size_t)(c * 64 + o) * 256;
    size_t pb = (size_t)(b * 64 + c) * 512;
#pragma unroll
    for (int mc = 0; mc < 4; ++mc) {
      int m = mc * 64 + m2;
      float r = wr[wbx + m];
      float im = wi[wbx + m];
      float2 x0 = Xp[pb + m];
      float2 x1 = Xp[pb + 256 + m];
      float xvx = x0.x + x1.x, xvy = x0.y + x1.y;
      yr[mc] += xvx * r - xvy * im;
      yi[mc] += xvx * im + xvy * r;
    }
  }
#pragma unroll
  for (int mc = 0; mc < 4; ++mc) red[cg * 256 + mc * 64 + m2] = make_float2(yr[mc], yi[mc]);
  __syncthreads();
  {
    float sx = 0.f, sy = 0.f;
#pragma unroll
    for (int g2 = 0; g2 < 4; ++g2) {
      float2 v = red[g2 * 256 + tid];
      sx += v.x; sy += v.y;
    }
    Ys[tid] = make_float2(sx, sy);
  }
  __syncthreads();

  // inv phase: y = tid
  int y = tid;
  float gr[16], gi[16];
#pragma unroll
  for (int k = 0; k < 16; ++k) { gr[k] = 0.f; gi[k] = 0.f; }
  for (int ky = 0; ky < 16; ++ky) {
    float c = cosT[ky * 256 + y], s = sinT[ky * 256 + y];
#pragma unroll
    for (int kx = 0; kx < 16; ++kx) {
      float2 v = Ys[ky * 16 + kx];
      gr[kx] += c * v.x - s * v.y;
      gi[kx] += c * v.y + s * v.x;
    }
  }
  float val[32];
  const float sc = 1.0f / 65536.0f;
#pragma unroll
  for (int kx = 0; kx < 16; ++kx) {
    float m = (kx == 0) ? sc : 2.0f * sc;
    val[2 * kx] = gr[kx] * m;
    val[2 * kx + 1] = gi[kx] * m;
  }
  size_t gb = ((size_t)(b * 64 + o) * 256 + y) * 32;
#pragma unroll
  for (int q = 0; q < 8; ++q) {
    ushort4 H, L;
#pragma unroll
    for (int r = 0; r < 4; ++r) {
      float v = val[q * 4 + r];
      unsigned hi = bf16rne(v);
      ((ushort*)&H)[r] = (ushort)hi;
      ((ushort*)&L)[r] = (ushort)bf16rne(v - bf16tof(hi));
    }
    *(ushort4*)&gh[gb + q * 4] = H;
    *(ushort4*)&gl[gb + q * 4] = L;
  }
}

// ---------- K_LAYER: half-row block (b,y,xh). w/g staged; coalesced epilogue;
// fused half-row x-DFT writing A2 partial xh. Grid 2048, LDS 28.7 KB -> 5 blocks/CU. ----------
__global__ __launch_bounds__(256) void k_layer(const ushort* __restrict__ hh,
                                               const ushort* __restrict__ gh, const ushort* __restrict__ gl,
                                               const ushort* __restrict__ wh, const ushort* __restrict__ wl,
                                               const float* __restrict__ wb,
                                               const ushort* __restrict__ e2h, const ushort* __restrict__ e2l,
                                               const ushort* __restrict__ eah, const ushort* __restrict__ eal,
                                               ushort* __restrict__ oh,
                                               float* __restrict__ A2, int do_dft) {
  int bid = blockIdx.x;                 // 2048 = b*512 + y*2 + xh
  int b = bid >> 9, y = (bid >> 1) & 255, xh = bid & 1;
  int tid = threadIdx.x;
  int lane = tid & 63, wv = tid >> 6;
  int lm = lane & 15, lg = lane >> 4;
  size_t nbase = (size_t)(b * 256 + y) * 256;

  // staging: wsH[64*72]@0, wsL@4608, gsH[64*40]@9216, gsL@11776 (14336 ushorts = 28672 B)
  // phase-B: Xs[128*66] = 8448 ushorts aliases the front.
  __shared__ __align__(16) ushort smem[14336];
  __shared__ float wbs[64];
  ushort* wsH = smem;
  ushort* wsL = smem + 4608;
  ushort* gsH = smem + 9216;
  ushort* gsL = smem + 11776;
  ushort* Xs  = smem;

  // stage w
#pragma unroll
  for (int rep = 0; rep < 2; ++rep) {
    int flat = rep * 2048 + tid * 8;
    int o = flat >> 6, cc = flat & 63;
    *(short8*)&wsH[o * 72 + cc] = *(const short8*)&wh[flat];
    *(short8*)&wsL[o * 72 + cc] = *(const short8*)&wl[flat];
  }
  // stage g
  {
    int o = tid >> 2, i = (tid & 3) * 8;
    size_t ga = ((size_t)(b * 64 + o) * 256 + y) * 32 + i;
    *(short8*)&gsH[o * 40 + i] = *(const short8*)&gh[ga];
    *(short8*)&gsL[o * 40 + i] = *(const short8*)&gl[ga];
  }
  if (tid < 64) wbs[tid] = wb[tid];
  __syncthreads();

  // B fragments upfront: 4 h loads + 2 e2 loads (independent)
  short8 bh0[2], bh1[2], ehv[2], elv[2];
#pragma unroll
  for (int ni = 0; ni < 2; ++ni) {
    int xx = xh * 128 + wv * 32 + ni * 16 + lm;
    size_t hb = (nbase + xx) * 64 + lg * 8;
    bh0[ni] = *(const short8*)&hh[hb];
    bh1[ni] = *(const short8*)&hh[hb + 32];
    ehv[ni] = *(const short8*)&e2h[xx * 32 + lg * 8];
    elv[ni] = *(const short8*)&e2l[xx * 32 + lg * 8];
  }

  f32x4 acc[4][2];
#pragma unroll
  for (int mi = 0; mi < 4; ++mi)
#pragma unroll
    for (int ni = 0; ni < 2; ++ni) acc[mi][ni] = (f32x4){0.f, 0.f, 0.f, 0.f};

#pragma unroll
  for (int mi = 0; mi < 4; ++mi) {
    int o = mi * 16 + lm;
    short8 ah0 = *(const short8*)&wsH[o * 72 + lg * 8];
    short8 al0 = *(const short8*)&wsL[o * 72 + lg * 8];
    short8 ah1 = *(const short8*)&wsH[o * 72 + 32 + lg * 8];
    short8 al1 = *(const short8*)&wsL[o * 72 + 32 + lg * 8];
    short8 gah = *(const short8*)&gsH[o * 40 + lg * 8];
    short8 gal = *(const short8*)&gsL[o * 40 + lg * 8];
#pragma unroll
    for (int ni = 0; ni < 2; ++ni) {
      acc[mi][ni] = __builtin_amdgcn_mfma_f32_16x16x32_bf16(ah0, bh0[ni], acc[mi][ni], 0, 0, 0);
      acc[mi][ni] = __builtin_amdgcn_mfma_f32_16x16x32_bf16(al0, bh0[ni], acc[mi][ni], 0, 0, 0);
      acc[mi][ni] = __builtin_amdgcn_mfma_f32_16x16x32_bf16(ah1, bh1[ni], acc[mi][ni], 0, 0, 0);
      acc[mi][ni] = __builtin_amdgcn_mfma_f32_16x16x32_bf16(al1, bh1[ni], acc[mi][ni], 0, 0, 0);
      acc[mi][ni] = __builtin_amdgcn_mfma_f32_16x16x32_bf16(gah, ehv[ni], acc[mi][ni], 0, 0, 0);
      acc[mi][ni] = __builtin_amdgcn_mfma_f32_16x16x32_bf16(gah, elv[ni], acc[mi][ni], 0, 0, 0);
      acc[mi][ni] = __builtin_amdgcn_mfma_f32_16x16x32_bf16(gal, ehv[ni], acc[mi][ni], 0, 0, 0);
    }
  }

  // epilogue: bias + GELU -> bf16 -> Xs[x_local][o] stride 66 (aliases staging)
  __syncthreads();
#pragma unroll
  for (int mi = 0; mi < 4; ++mi)
#pragma unroll
    for (int ni = 0; ni < 2; ++ni) {
      int xl = wv * 32 + ni * 16 + lm;
      ushort4 H;
#pragma unroll
      for (int r = 0; r < 4; ++r) {
        int o = mi * 16 + lg * 4 + r;
        float ge = gelu(acc[mi][ni][r] + wbs[o]);
        ((ushort*)&H)[r] = (ushort)bf16rne(ge);
      }
      *(ushort4*)&Xs[xl * 66 + mi * 16 + lg * 4] = H;
    }
  __syncthreads();
  // coalesced 16B stores of the half row
  size_t rowb = nbase + xh * 128;
#pragma unroll
  for (int rep = 0; rep < 4; ++rep) {
    int flat = rep * 256 + tid;       // (pixel p, 16B chunk)
    int p = flat >> 3, off = (flat & 7) * 8;
    short8 vH = *(const short8*)&Xs[p * 66 + off];
    *(short8*)&oh[(rowb + p) * 64 + off] = vH;
  }

  // fused half-row x-DFT of h_next: wave = c 16-slice, writes A2 partial xh
  if (do_dft) {
    f32x4 d0 = (f32x4){0.f, 0.f, 0.f, 0.f};
    f32x4 d1 = (f32x4){0.f, 0.f, 0.f, 0.f};
    int c = wv * 16 + lm;
#pragma unroll
    for (int kc = 0; kc < 4; ++kc) {
      int xl0 = kc * 32 + lg * 8;
      short8 bh;
#pragma unroll
      for (int i = 0; i < 8; ++i) bh[i] = (short)Xs[(xl0 + i) * 66 + c];
      int x0g = xh * 128 + xl0;
      short8 a0h = *(const short8*)&eah[lm * 256 + x0g];
      short8 a0l = *(const short8*)&eal[lm * 256 + x0g];
      short8 a1h = *(const short8*)&eah[(16 + lm) * 256 + x0g];
      short8 a1l = *(const short8*)&eal[(16 + lm) * 256 + x0g];
      d0 = __builtin_amdgcn_mfma_f32_16x16x32_bf16(a0h, bh, d0, 0, 0, 0);
      d0 = __builtin_amdgcn_mfma_f32_16x16x32_bf16(a0l, bh, d0, 0, 0, 0);
      d1 = __builtin_amdgcn_mfma_f32_16x16x32_bf16(a1h, bh, d1, 0, 0, 0);
      d1 = __builtin_amdgcn_mfma_f32_16x16x32_bf16(a1l, bh, d1, 0, 0, 0);
    }
    size_t row = ((size_t)(b * 64 + c) * 256 + y) * 64 + xh * 32;
    *(float4*)&A2[row + lg * 4] = make_float4(d0[0], d0[1], d0[2], d0[3]);
    *(float4*)&A2[row + 16 + lg * 4] = make_float4(d1[0], d1[1], d1[2], d1[3]);
  }
}

// ---------- K_FINAL: LDS-staged fc1 weights. grid 4096 ----------
__global__ __launch_bounds__(256) void k_final(const ushort* __restrict__ hh,
                                               const ushort* __restrict__ w1h, const ushort* __restrict__ w1l,
                                               const float* __restrict__ b1, const float* __restrict__ w2,
                                               const float* __restrict__ b2, float* __restrict__ out) {
  int bid = blockIdx.x;                 // 4096 = b*1024 + y*4 + xq
  int b = bid >> 10, y = (bid >> 2) & 255, xq = bid & 3;
  int tid = threadIdx.x;
  int lane = tid & 63, wave = tid >> 6;
  int lm = lane & 15, lg = lane >> 4;
  int x = xq * 64 + wave * 16 + lm;
  size_t nb = (size_t)(b * 256 + y) * 256 + x;

  __shared__ __align__(16) ushort w1sH[128 * 72], w1sL[128 * 72];
  __shared__ float b1s[128], w2s[128];

#pragma unroll
  for (int rep = 0; rep < 4; ++rep) {
    int flat = rep * 2048 + tid * 8;
    int j = flat >> 6, cc = flat & 63;
    *(short8*)&w1sH[j * 72 + cc] = *(const short8*)&w1h[flat];
    *(short8*)&w1sL[j * 72 + cc] = *(const short8*)&w1l[flat];
  }
  if (tid < 128) { b1s[tid] = b1[tid]; w2s[tid] = w2[tid]; }
  __syncthreads();

  short8 bh0 = *(const short8*)&hh[nb * 64 + lg * 8];
  short8 bh1 = *(const short8*)&hh[nb * 64 + 32 + lg * 8];

  f32x4 acc[8];
#pragma unroll
  for (int mi = 0; mi < 8; ++mi) acc[mi] = (f32x4){0.f, 0.f, 0.f, 0.f};

#pragma unroll
  for (int mi = 0; mi < 8; ++mi) {
    int j = mi * 16 + lm;
    short8 ah0 = *(const short8*)&w1sH[j * 72 + lg * 8];
    short8 al0 = *(const short8*)&w1sL[j * 72 + lg * 8];
    acc[mi] = __builtin_amdgcn_mfma_f32_16x16x32_bf16(ah0, bh0, acc[mi], 0, 0, 0);
    acc[mi] = __builtin_amdgcn_mfma_f32_16x16x32_bf16(al0, bh0, acc[mi], 0, 0, 0);
    short8 ah1 = *(const short8*)&w1sH[j * 72 + 32 + lg * 8];
    short8 al1 = *(const short8*)&w1sL[j * 72 + 32 + lg * 8];
    acc[mi] = __builtin_amdgcn_mfma_f32_16x16x32_bf16(ah1, bh1, acc[mi], 0, 0, 0);
    acc[mi] = __builtin_amdgcn_mfma_f32_16x16x32_bf16(al1, bh1, acc[mi], 0, 0, 0);
  }

  float p = 0.f;
#pragma unroll
  for (int mi = 0; mi < 8; ++mi)
#pragma unroll
    for (int r = 0; r < 4; ++r) {
      int j = mi * 16 + lg * 4 + r;
      p += w2s[j] * gelu(acc[mi][r] + b1s[j]);
    }
  p += __shfl_xor(p, 16);
  p += __shfl_xor(p, 32);
  if (lg == 0) {
    out[(b * 256 + y) * 256 + x] = p + b2[0];
  }
}

extern "C" void kernel_launch(void* const* d_in, const int* in_sizes, int n_in,
                              void* d_out, int out_size, void* d_ws, size_t ws_size,
                              hipStream_t stream) {
  const float* x       = (const float*)d_in[0];
  const float* fc0_w   = (const float*)d_in[1];
  const float* fc0_b   = (const float*)d_in[2];
  const float* spec_wr = (const float*)d_in[3];
  const float* spec_wi = (const float*)d_in[4];
  const float* w_w     = (const float*)d_in[5];
  const float* w_b     = (const float*)d_in[6];
  const float* fc1_w   = (const float*)d_in[7];
  const float* fc1_b   = (const float*)d_in[8];
  const float* fc2_w   = (const float*)d_in[9];
  const float* fc2_b   = (const float*)d_in[10];
  float* out = (float*)d_out;

  char* ws = (char*)d_ws;
  ushort* h0h  = (ushort*)ws;                              // 33554432 B
  ushort* h1h  = (ushort*)(ws + 33554432);                 // 33554432 B
  float*  A2   = (float*)(ws + 67108864);                  // 16777216 B
  ushort* gh   = (ushort*)(ws + 83886080);                 // 4194304 B
  ushort* gl   = (ushort*)(ws + 88080384);                 // 4194304 B
  float2* Xp   = (float2*)(ws + 92274688);                 // 1048576 B
  float*  cosT = (float*)(ws + 93323264);                  // 16384 B
  float*  sinT = (float*)(ws + 93339648);                  // 16384 B
  ushort* eah  = (ushort*)(ws + 93356032);                 // 16384 B
  ushort* eal  = (ushort*)(ws + 93372416);                 // 16384 B
  ushort* e2h  = (ushort*)(ws + 93388800);                 // 16384 B
  ushort* e2l  = (ushort*)(ws + 93405184);                 // 16384 B
  ushort* wWh  = (ushort*)(ws + 93421568);                 // 32768 B
  ushort* wWl  = (ushort*)(ws + 93454336);                 // 32768 B
  ushort* w1h  = (ushort*)(ws + 93487104);                 // 16384 B
  ushort* w1l  = (ushort*)(ws + 93503488);                 // 16384 B

  k_tables<<<144, 256, 0, stream>>>(cosT, sinT, eah, eal, e2h, e2l,
                                    w_w, fc1_w, wWh, wWl, w1h, w1l);
  k_fc0<<<1024, 256, 0, stream>>>(x, fc0_w, fc0_b, eah, eal, h0h, A2);
  ushort* hch = h0h;
  ushort* hnh = h1h;
  for (int l = 0; l < 4; ++l) {
    k_f2<<<512, 256, 0, stream>>>(A2, cosT, sinT, Xp, (l == 0) ? 1 : 2);
    k_mixinv<<<256, 256, 0, stream>>>(Xp, spec_wr + (size_t)l * 1048576,
                                      spec_wi + (size_t)l * 1048576, cosT, sinT, gh, gl);
    k_layer<<<2048, 256, 0, stream>>>(hch, gh, gl, wWh + l * 4096, wWl + l * 4096,
                                      w_b + l * 64, e2h, e2l, eah, eal, hnh, A2, (l < 3) ? 1 : 0);
    ushort* t = hch; hch = hnh; hnh = t;
  }
  k_final<<<4096, 256, 0, stream>>>(hch, w1h, w1l, fc1_b, fc2_w, fc2_b, out);
}

// Round 17
// 338.785 us; speedup vs baseline: 1.0337x; 1.0337x over previous
//
#include <hip/hip_runtime.h>
#include <math.h>

#define HW 65536

typedef __attribute__((ext_vector_type(8))) short short8;
typedef __attribute__((ext_vector_type(4))) float f32x4;

__device__ __forceinline__ unsigned bf16rne(float f) {
  union { float f; unsigned u; } a; a.f = f;
  return (a.u + 0x7fffu + ((a.u >> 16) & 1u)) >> 16;
}
__device__ __forceinline__ float bf16tof(unsigned h) {
  union { unsigned u; float f; } a; a.u = h << 16;
  return a.f;
}
// fast gelu: Abramowitz-Stegun 7.1.26 erf, |abs err| <= 1.5e-7, branch-free
__device__ __forceinline__ float gelu(float v) {
  float ax = fabsf(v) * 0.70710678118654752f;
  float t = 1.0f / fmaf(0.3275911f, ax, 1.0f);
  float p = t * (0.254829592f +
           t * (-0.284496736f +
           t * (1.421413741f +
           t * (-1.453152027f +
           t * 1.061405429f))));
  float e = __expf(-ax * ax);
  float er = copysignf(fmaf(-p, e, 1.0f), v);
  return 0.5f * v * (1.0f + er);
}

// ---------- tables + weight pre-split (merged) ----------
__global__ __launch_bounds__(256) void k_tables(float* __restrict__ cosT, float* __restrict__ sinT,
                                                ushort* __restrict__ eah, ushort* __restrict__ eal,
                                                ushort* __restrict__ e2h, ushort* __restrict__ e2l,
                                                const float* __restrict__ ww, const float* __restrict__ w1,
                                                ushort* __restrict__ wh, ushort* __restrict__ wl,
                                                ushort* __restrict__ w1h, ushort* __restrict__ w1l) {
  int idx = blockIdx.x * 256 + threadIdx.x;   // 144*256 = 36864
  const float w = 0.0245436926061702596f;     // 2*pi/256
  if (idx < 4096) {
    int k = idx >> 8, xx = idx & 255;
    int t = (k * xx) & 255;
    float ang = (float)t * w;
    cosT[idx] = cosf(ang);
    sinT[idx] = sinf(ang);
  } else if (idx < 12288) {
    int e = idx - 4096;
    int j = e >> 8, xx = e & 255;
    int k = j >> 1;
    int t = (k * xx) & 255;
    float ang = (float)t * w;
    float val = (j & 1) ? -sinf(ang) : cosf(ang);
    unsigned hi = bf16rne(val);
    unsigned lo = bf16rne(val - bf16tof(hi));
    eah[j * 256 + xx] = (ushort)hi;
    eal[j * 256 + xx] = (ushort)lo;
    e2h[xx * 32 + j] = (ushort)hi;
    e2l[xx * 32 + j] = (ushort)lo;
  } else if (idx < 28672) {
    int j = idx - 12288;
    float v = ww[j];
    unsigned hi = bf16rne(v);
    wh[j] = (ushort)hi;
    wl[j] = (ushort)bf16rne(v - bf16tof(hi));
  } else {
    int j = idx - 28672;                      // 8192
    float v = w1[j];
    unsigned hi = bf16rne(v);
    w1h[j] = (ushort)hi;
    w1l[j] = (ushort)bf16rne(v - bf16tof(hi));
  }
}

// ---------- fc0: h plane (bf16) + fused full-row x-DFT (canonical A) ----------
// A canonical: A[((b*64+c)*256+y)*32 + j], j: permuted spectral index (s = lg*8+mt*4+r).
__global__ __launch_bounds__(256) void k_fc0(const float* __restrict__ x, const float* __restrict__ w,
                                             const float* __restrict__ b,
                                             const ushort* __restrict__ eah, const ushort* __restrict__ eal,
                                             ushort* __restrict__ hh, float* __restrict__ A) {
  int bid = blockIdx.x;                 // 1024 = B*H
  int bb = bid >> 8, y = bid & 255;
  int tid = threadIdx.x;
  __shared__ float ws[192];
  __shared__ float bs[64];
  __shared__ __align__(16) ushort XsH[256 * 66];
  if (tid < 192) ws[tid] = w[tid];
  if (tid < 64) bs[tid] = b[tid];
  __syncthreads();
  const float* xrow = x + ((size_t)(bb * 3) * 256 + y) * 256;
#pragma unroll
  for (int rep = 0; rep < 8; ++rep) {
    int flat = rep * 256 + tid;       // (pixel p, 8-c group q)
    int p = flat >> 3, q = flat & 7;
    float v0 = xrow[p], v1 = xrow[p + HW], v2 = xrow[p + 2 * HW];
    short8 H;
#pragma unroll
    for (int i = 0; i < 8; ++i) {
      int o = q * 8 + i;
      float v = bs[o] + ws[o * 3] * v0 + ws[o * 3 + 1] * v1 + ws[o * 3 + 2] * v2;
      H[i] = (short)bf16rne(v);
    }
    size_t nb = ((size_t)bid * 256 + p) * 64 + q * 8;
    *(short8*)&hh[nb] = H;
    *(short8*)&XsH[p * 66 + q * 8] = H;
  }
  __syncthreads();
  // fused F1: wave = c 16-slice, contract over full 256 x
  int lane = tid & 63, wv = tid >> 6;
  int lm = lane & 15, lg = lane >> 4;
  f32x4 d0 = (f32x4){0.f, 0.f, 0.f, 0.f};
  f32x4 d1 = (f32x4){0.f, 0.f, 0.f, 0.f};
  int c = wv * 16 + lm;
#pragma unroll
  for (int kc = 0; kc < 8; ++kc) {
    int x0 = kc * 32 + lg * 8;
    short8 bh;
#pragma unroll
    for (int i = 0; i < 8; ++i) bh[i] = (short)XsH[(x0 + i) * 66 + c];
    short8 a0h = *(const short8*)&eah[lm * 256 + x0];
    short8 a0l = *(const short8*)&eal[lm * 256 + x0];
    short8 a1h = *(const short8*)&eah[(16 + lm) * 256 + x0];
    short8 a1l = *(const short8*)&eal[(16 + lm) * 256 + x0];
    d0 = __builtin_amdgcn_mfma_f32_16x16x32_bf16(a0h, bh, d0, 0, 0, 0);
    d0 = __builtin_amdgcn_mfma_f32_16x16x32_bf16(a0l, bh, d0, 0, 0, 0);
    d1 = __builtin_amdgcn_mfma_f32_16x16x32_bf16(a1h, bh, d1, 0, 0, 0);
    d1 = __builtin_amdgcn_mfma_f32_16x16x32_bf16(a1l, bh, d1, 0, 0, 0);
  }
  size_t row = ((size_t)(bb * 64 + c) * 256 + y) * 32;
  *(float4*)&A[row + lg * 4] = make_float4(d0[0], d0[1], d0[2], d0[3]);
  *(float4*)&A[row + 16 + lg * 4] = make_float4(d1[0], d1[1], d1[2], d1[3]);
}

// ---------- F2: col DFT over y (y-split halves); reads canonical A; writes X partials ----------
__global__ __launch_bounds__(256) void k_f2(const float* __restrict__ A, const float* __restrict__ cosT,
                                            const float* __restrict__ sinT, float2* __restrict__ Xp) {
  int bid = blockIdx.x;                 // 512 = plane*2 + yh
  int plane = bid >> 1, yh = bid & 1;
  int tid = threadIdx.x;
  __shared__ float2 As[128 * 16];
  __shared__ float ct[16 * 129];
  __shared__ float stt[16 * 129];
  const float2* Ap = (const float2*)A + (size_t)plane * 4096;
#pragma unroll
  for (int rep = 0; rep < 8; ++rep) {
    int flat = rep * 256 + tid;       // 2048: y' (128) x j (16)
    As[flat] = Ap[yh * 2048 + flat];
  }
#pragma unroll
  for (int rep = 0; rep < 8; ++rep) {
    int flat = rep * 256 + tid;       // 2048: ky (16) x y' (128)
    int ky = flat >> 7, yp = flat & 127;
    ct[ky * 129 + yp] = cosT[ky * 256 + yh * 128 + yp];
    stt[ky * 129 + yp] = sinT[ky * 256 + yh * 128 + yp];
  }
  __syncthreads();
  int ky = tid >> 4, kx = tid & 15;
  float xr = 0.f, xi = 0.f;
#pragma unroll 4
  for (int yp = 0; yp < 128; ++yp) {
    float2 a = As[yp * 16 + kx];
    float c = ct[ky * 129 + yp], s = stt[ky * 129 + yp];
    xr += c * a.x + s * a.y;
    xi += c * a.y - s * a.x;
  }
  Xp[(size_t)plane * 512 + yh * 256 + tid] = make_float2(xr, xi);
}

// ---------- MIXINV: fused mix + inv1. Block = (o, b). ----------
__global__ __launch_bounds__(256) void k_mixinv(const float2* __restrict__ Xp,
                                                const float* __restrict__ wr, const float* __restrict__ wi,
                                                const float* __restrict__ cosT, const float* __restrict__ sinT,
                                                ushort* __restrict__ gh, ushort* __restrict__ gl) {
  int bid = blockIdx.x;                 // 256 = o*4 + b
  int o = bid >> 2, b = bid & 3;
  int tid = threadIdx.x;
  int cg = tid >> 6, m2 = tid & 63;
  __shared__ float2 red[1024];
  __shared__ float2 Ys[256];

  float yr[4] = {0.f, 0.f, 0.f, 0.f}, yi[4] = {0.f, 0.f, 0.f, 0.f};
#pragma unroll 4
  for (int cc = 0; cc < 16; ++cc) {
    int c = cg * 16 + cc;
    size_t wbx = (size_t)(c * 64 + o) * 256;
    size_t pb = (size_t)(b * 64 + c) * 512;
#pragma unroll
    for (int mc = 0; mc < 4; ++mc) {
      int m = mc * 64 + m2;
      float r = wr[wbx + m];
      float im = wi[wbx + m];
      float2 x0 = Xp[pb + m];
      float2 x1 = Xp[pb + 256 + m];
      float xvx = x0.x + x1.x, xvy = x0.y + x1.y;
      yr[mc] += xvx * r - xvy * im;
      yi[mc] += xvx * im + xvy * r;
    }
  }
#pragma unroll
  for (int mc = 0; mc < 4; ++mc) red[cg * 256 + mc * 64 + m2] = make_float2(yr[mc], yi[mc]);
  __syncthreads();
  {
    float sx = 0.f, sy = 0.f;
#pragma unroll
    for (int g2 = 0; g2 < 4; ++g2) {
      float2 v = red[g2 * 256 + tid];
      sx += v.x; sy += v.y;
    }
    Ys[tid] = make_float2(sx, sy);
  }
  __syncthreads();

  // inv phase: y = tid
  int y = tid;
  float gr[16], gi[16];
#pragma unroll
  for (int k = 0; k < 16; ++k) { gr[k] = 0.f; gi[k] = 0.f; }
  for (int ky = 0; ky < 16; ++ky) {
    float c = cosT[ky * 256 + y], s = sinT[ky * 256 + y];
#pragma unroll
    for (int kx = 0; kx < 16; ++kx) {
      float2 v = Ys[ky * 16 + kx];
      gr[kx] += c * v.x - s * v.y;
      gi[kx] += c * v.y + s * v.x;
    }
  }
  float val[32];
  const float sc = 1.0f / 65536.0f;
#pragma unroll
  for (int kx = 0; kx < 16; ++kx) {
    float m = (kx == 0) ? sc : 2.0f * sc;
    val[2 * kx] = gr[kx] * m;
    val[2 * kx + 1] = gi[kx] * m;
  }
  size_t gb = ((size_t)(b * 64 + o) * 256 + y) * 32;
#pragma unroll
  for (int q = 0; q < 8; ++q) {
    ushort4 H, L;
#pragma unroll
    for (int r = 0; r < 4; ++r) {
      float v = val[q * 4 + r];
      unsigned hi = bf16rne(v);
      ((ushort*)&H)[r] = (ushort)hi;
      ((ushort*)&L)[r] = (ushort)bf16rne(v - bf16tof(hi));
    }
    *(ushort4*)&gh[gb + q * 4] = H;
    *(ushort4*)&gl[gb + q * 4] = L;
  }
}

// ---------- K_LAYER: full-row block (b,y). w/g staged once; 8 h-loads in flight/thread;
// coalesced epilogue; fused full-row x-DFT writing canonical A. setprio around MFMA. ----------
__global__ __launch_bounds__(256) void k_layer(const ushort* __restrict__ hh,
                                               const ushort* __restrict__ gh, const ushort* __restrict__ gl,
                                               const ushort* __restrict__ wh, const ushort* __restrict__ wl,
                                               const float* __restrict__ wb,
                                               const ushort* __restrict__ e2h, const ushort* __restrict__ e2l,
                                               const ushort* __restrict__ eah, const ushort* __restrict__ eal,
                                               ushort* __restrict__ oh,
                                               float* __restrict__ A, int do_dft) {
  int bid = blockIdx.x;                 // 1024 = b*256 + y
  int b = bid >> 8, y = bid & 255;
  int tid = threadIdx.x;
  int lane = tid & 63, wv = tid >> 6;
  int lm = lane & 15, lg = lane >> 4;
  size_t nbase = (size_t)(b * 256 + y) * 256;

  // phase-A: wsH[64*72]@0, wsL@4608, gsH[64*40]@9216, gsL@11776 (ushorts)
  // phase-B (after barrier): Xs[256*66] aliases everything.
  __shared__ __align__(16) ushort smem[16896];
  __shared__ float wbs[64];
  ushort* wsH = smem;
  ushort* wsL = smem + 4608;
  ushort* gsH = smem + 9216;
  ushort* gsL = smem + 11776;
  ushort* Xs  = smem;

  // stage w (once per row)
#pragma unroll
  for (int rep = 0; rep < 2; ++rep) {
    int flat = rep * 2048 + tid * 8;
    int o = flat >> 6, cc = flat & 63;
    *(short8*)&wsH[o * 72 + cc] = *(const short8*)&wh[flat];
    *(short8*)&wsL[o * 72 + cc] = *(const short8*)&wl[flat];
  }
  // stage g (once per row)
  {
    int o = tid >> 2, i = (tid & 3) * 8;
    size_t ga = ((size_t)(b * 64 + o) * 256 + y) * 32 + i;
    *(short8*)&gsH[o * 40 + i] = *(const short8*)&gh[ga];
    *(short8*)&gsL[o * 40 + i] = *(const short8*)&gl[ga];
  }
  if (tid < 64) wbs[tid] = wb[tid];
  __syncthreads();

  // all B fragments upfront: 8 independent 16B h loads + 8 e2 loads
  short8 bh0[4], bh1[4], ehv[4], elv[4];
#pragma unroll
  for (int ni = 0; ni < 4; ++ni) {
    int xx = wv * 64 + ni * 16 + lm;
    size_t hb = (nbase + xx) * 64 + lg * 8;
    bh0[ni] = *(const short8*)&hh[hb];
    bh1[ni] = *(const short8*)&hh[hb + 32];
    ehv[ni] = *(const short8*)&e2h[xx * 32 + lg * 8];
    elv[ni] = *(const short8*)&e2l[xx * 32 + lg * 8];
  }

  f32x4 acc[4][4];
#pragma unroll
  for (int mi = 0; mi < 4; ++mi)
#pragma unroll
    for (int ni = 0; ni < 4; ++ni) acc[mi][ni] = (f32x4){0.f, 0.f, 0.f, 0.f};

  __builtin_amdgcn_s_setprio(1);
#pragma unroll
  for (int mi = 0; mi < 4; ++mi) {
    int o = mi * 16 + lm;
    short8 ah0 = *(const short8*)&wsH[o * 72 + lg * 8];
    short8 al0 = *(const short8*)&wsL[o * 72 + lg * 8];
    short8 ah1 = *(const short8*)&wsH[o * 72 + 32 + lg * 8];
    short8 al1 = *(const short8*)&wsL[o * 72 + 32 + lg * 8];
    short8 gah = *(const short8*)&gsH[o * 40 + lg * 8];
    short8 gal = *(const short8*)&gsL[o * 40 + lg * 8];
#pragma unroll
    for (int ni = 0; ni < 4; ++ni) {
      acc[mi][ni] = __builtin_amdgcn_mfma_f32_16x16x32_bf16(ah0, bh0[ni], acc[mi][ni], 0, 0, 0);
      acc[mi][ni] = __builtin_amdgcn_mfma_f32_16x16x32_bf16(al0, bh0[ni], acc[mi][ni], 0, 0, 0);
      acc[mi][ni] = __builtin_amdgcn_mfma_f32_16x16x32_bf16(ah1, bh1[ni], acc[mi][ni], 0, 0, 0);
      acc[mi][ni] = __builtin_amdgcn_mfma_f32_16x16x32_bf16(al1, bh1[ni], acc[mi][ni], 0, 0, 0);
      acc[mi][ni] = __builtin_amdgcn_mfma_f32_16x16x32_bf16(gah, ehv[ni], acc[mi][ni], 0, 0, 0);
      acc[mi][ni] = __builtin_amdgcn_mfma_f32_16x16x32_bf16(gah, elv[ni], acc[mi][ni], 0, 0, 0);
      acc[mi][ni] = __builtin_amdgcn_mfma_f32_16x16x32_bf16(gal, ehv[ni], acc[mi][ni], 0, 0, 0);
    }
  }
  __builtin_amdgcn_s_setprio(0);

  // epilogue: bias + GELU -> bf16 -> Xs[x][o] stride 66 (aliases staging)
  __syncthreads();
#pragma unroll
  for (int mi = 0; mi < 4; ++mi)
#pragma unroll
    for (int ni = 0; ni < 4; ++ni) {
      int xx = wv * 64 + ni * 16 + lm;
      ushort4 H;
#pragma unroll
      for (int r = 0; r < 4; ++r) {
        int o = mi * 16 + lg * 4 + r;
        float ge = gelu(acc[mi][ni][r] + wbs[o]);
        ((ushort*)&H)[r] = (ushort)bf16rne(ge);
      }
      *(ushort4*)&Xs[xx * 66 + mi * 16 + lg * 4] = H;
    }
  __syncthreads();
  // coalesced 16B stores of the whole row
#pragma unroll
  for (int rep = 0; rep < 8; ++rep) {
    int flat = rep * 256 + tid;       // (pixel p, 16B chunk)
    int p = flat >> 3, off = (flat & 7) * 8;
    short8 vH = *(const short8*)&Xs[p * 66 + off];
    *(short8*)&oh[(nbase + p) * 64 + off] = vH;
  }

  // fused full-row x-DFT of h_next: wave = c 16-slice, canonical A write
  if (do_dft) {
    f32x4 d0 = (f32x4){0.f, 0.f, 0.f, 0.f};
    f32x4 d1 = (f32x4){0.f, 0.f, 0.f, 0.f};
    int c = wv * 16 + lm;
#pragma unroll
    for (int kc = 0; kc < 8; ++kc) {
      int x0 = kc * 32 + lg * 8;
      short8 bh;
#pragma unroll
      for (int i = 0; i < 8; ++i) bh[i] = (short)Xs[(x0 + i) * 66 + c];
      short8 a0h = *(const short8*)&eah[lm * 256 + x0];
      short8 a0l = *(const short8*)&eal[lm * 256 + x0];
      short8 a1h = *(const short8*)&eah[(16 + lm) * 256 + x0];
      short8 a1l = *(const short8*)&eal[(16 + lm) * 256 + x0];
      d0 = __builtin_amdgcn_mfma_f32_16x16x32_bf16(a0h, bh, d0, 0, 0, 0);
      d0 = __builtin_amdgcn_mfma_f32_16x16x32_bf16(a0l, bh, d0, 0, 0, 0);
      d1 = __builtin_amdgcn_mfma_f32_16x16x32_bf16(a1h, bh, d1, 0, 0, 0);
      d1 = __builtin_amdgcn_mfma_f32_16x16x32_bf16(a1l, bh, d1, 0, 0, 0);
    }
    size_t row = ((size_t)(b * 64 + c) * 256 + y) * 32;
    *(float4*)&A[row + lg * 4] = make_float4(d0[0], d0[1], d0[2], d0[3]);
    *(float4*)&A[row + 16 + lg * 4] = make_float4(d1[0], d1[1], d1[2], d1[3]);
  }
}

// ---------- K_FINAL: LDS-staged fc1 weights. grid 4096 ----------
__global__ __launch_bounds__(256) void k_final(const ushort* __restrict__ hh,
                                               const ushort* __restrict__ w1h, const ushort* __restrict__ w1l,
                                               const float* __restrict__ b1, const float* __restrict__ w2,
                                               const float* __restrict__ b2, float* __restrict__ out) {
  int bid = blockIdx.x;                 // 4096 = b*1024 + y*4 + xq
  int b = bid >> 10, y = (bid >> 2) & 255, xq = bid & 3;
  int tid = threadIdx.x;
  int lane = tid & 63, wave = tid >> 6;
  int lm = lane & 15, lg = lane >> 4;
  int x = xq * 64 + wave * 16 + lm;
  size_t nb = (size_t)(b * 256 + y) * 256 + x;

  __shared__ __align__(16) ushort w1sH[128 * 72], w1sL[128 * 72];
  __shared__ float b1s[128], w2s[128];

#pragma unroll
  for (int rep = 0; rep < 4; ++rep) {
    int flat = rep * 2048 + tid * 8;
    int j = flat >> 6, cc = flat & 63;
    *(short8*)&w1sH[j * 72 + cc] = *(const short8*)&w1h[flat];
    *(short8*)&w1sL[j * 72 + cc] = *(const short8*)&w1l[flat];
  }
  if (tid < 128) { b1s[tid] = b1[tid]; w2s[tid] = w2[tid]; }
  __syncthreads();

  short8 bh0 = *(const short8*)&hh[nb * 64 + lg * 8];
  short8 bh1 = *(const short8*)&hh[nb * 64 + 32 + lg * 8];

  f32x4 acc[8];
#pragma unroll
  for (int mi = 0; mi < 8; ++mi) acc[mi] = (f32x4){0.f, 0.f, 0.f, 0.f};

  __builtin_amdgcn_s_setprio(1);
#pragma unroll
  for (int mi = 0; mi < 8; ++mi) {
    int j = mi * 16 + lm;
    short8 ah0 = *(const short8*)&w1sH[j * 72 + lg * 8];
    short8 al0 = *(const short8*)&w1sL[j * 72 + lg * 8];
    acc[mi] = __builtin_amdgcn_mfma_f32_16x16x32_bf16(ah0, bh0, acc[mi], 0, 0, 0);
    acc[mi] = __builtin_amdgcn_mfma_f32_16x16x32_bf16(al0, bh0, acc[mi], 0, 0, 0);
    short8 ah1 = *(const short8*)&w1sH[j * 72 + 32 + lg * 8];
    short8 al1 = *(const short8*)&w1sL[j * 72 + 32 + lg * 8];
    acc[mi] = __builtin_amdgcn_mfma_f32_16x16x32_bf16(ah1, bh1, acc[mi], 0, 0, 0);
    acc[mi] = __builtin_amdgcn_mfma_f32_16x16x32_bf16(al1, bh1, acc[mi], 0, 0, 0);
  }
  __builtin_amdgcn_s_setprio(0);

  float p = 0.f;
#pragma unroll
  for (int mi = 0; mi < 8; ++mi)
#pragma unroll
    for (int r = 0; r < 4; ++r) {
      int j = mi * 16 + lg * 4 + r;
      p += w2s[j] * gelu(acc[mi][r] + b1s[j]);
    }
  p += __shfl_xor(p, 16);
  p += __shfl_xor(p, 32);
  if (lg == 0) {
    out[(b * 256 + y) * 256 + x] = p + b2[0];
  }
}

extern "C" void kernel_launch(void* const* d_in, const int* in_sizes, int n_in,
                              void* d_out, int out_size, void* d_ws, size_t ws_size,
                              hipStream_t stream) {
  const float* x       = (const float*)d_in[0];
  const float* fc0_w   = (const float*)d_in[1];
  const float* fc0_b   = (const float*)d_in[2];
  const float* spec_wr = (const float*)d_in[3];
  const float* spec_wi = (const float*)d_in[4];
  const float* w_w     = (const float*)d_in[5];
  const float* w_b     = (const float*)d_in[6];
  const float* fc1_w   = (const float*)d_in[7];
  const float* fc1_b   = (const float*)d_in[8];
  const float* fc2_w   = (const float*)d_in[9];
  const float* fc2_b   = (const float*)d_in[10];
  float* out = (float*)d_out;

  char* ws = (char*)d_ws;
  ushort* h0h  = (ushort*)ws;                              // 33554432 B
  ushort* h1h  = (ushort*)(ws + 33554432);                 // 33554432 B
  float*  A    = (float*)(ws + 67108864);                  // 8388608 B
  ushort* gh   = (ushort*)(ws + 75497472);                 // 4194304 B
  ushort* gl   = (ushort*)(ws + 79691776);                 // 4194304 B
  float2* Xp   = (float2*)(ws + 83886080);                 // 1048576 B
  float*  cosT = (float*)(ws + 85458944);                  // 16384 B
  float*  sinT = (float*)(ws + 85475328);                  // 16384 B
  ushort* eah  = (ushort*)(ws + 85491712);                 // 16384 B
  ushort* eal  = (ushort*)(ws + 85508096);                 // 16384 B
  ushort* e2h  = (ushort*)(ws + 85524480);                 // 16384 B
  ushort* e2l  = (ushort*)(ws + 85540864);                 // 16384 B
  ushort* wWh  = (ushort*)(ws + 85557248);                 // 32768 B
  ushort* wWl  = (ushort*)(ws + 85590016);                 // 32768 B
  ushort* w1h  = (ushort*)(ws + 85622784);                 // 16384 B
  ushort* w1l  = (ushort*)(ws + 85639168);                 // 16384 B

  k_tables<<<144, 256, 0, stream>>>(cosT, sinT, eah, eal, e2h, e2l,
                                    w_w, fc1_w, wWh, wWl, w1h, w1l);
  k_fc0<<<1024, 256, 0, stream>>>(x, fc0_w, fc0_b, eah, eal, h0h, A);
  ushort* hch = h0h;
  ushort* hnh = h1h;
  for (int l = 0; l < 4; ++l) {
    k_f2<<<512, 256, 0, stream>>>(A, cosT, sinT, Xp);
    k_mixinv<<<256, 256, 0, stream>>>(Xp, spec_wr + (size_t)l * 1048576,
                                      spec_wi + (size_t)l * 1048576, cosT, sinT, gh, gl);
    k_layer<<<1024, 256, 0, stream>>>(hch, gh, gl, wWh + l * 4096, wWl + l * 4096,
                                      w_b + l * 64, e2h, e2l, eah, eal, hnh, A, (l < 3) ? 1 : 0);
    ushort* t = hch; hch = hnh; hnh = t;
  }
  k_final<<<4096, 256, 0, stream>>>(hch, w1h, w1l, fc1_b, fc2_w, fc2_b, out);
}